// Round 4
// baseline (217.086 us; speedup 1.0000x reference)
//
#include <hip/hip_runtime.h>
#include <math.h>

// SpatialEncodeAgent: segment_max of agent_encodings (N,64) into a B*100*100
// grid, output [B, C, S, S] f32, 0 for empty cells.
//
// Round-4: CSR gather. Round 2/3's linked-list walk (agent = next[agent]) is
// a serially-dependent pointer chase (~3.1 L2/HBM round trips per cell) and
// each next[] read drags a 128B line for 4B. CSR build (count -> scan ->
// fill) makes the gather loop dependence-free: trip count known upfront,
// order[] read near-contiguously, enc row loads software-pipelined by the
// compiler. fmax is exactly commutative -> fill-order nondeterminism is
// bitwise-safe.

#define S_DIM 100
#define CELLS_PER_B (S_DIM * S_DIM)  // 10000
#define C_DIM 64
#define CPB 32  // cells per gather block

// ---------------- CSR build ----------------

__global__ void init_counts(int* __restrict__ cnt, int n) {
    const int stride = gridDim.x * blockDim.x;
    for (int i = blockIdx.x * blockDim.x + threadIdx.x; i < n; i += stride)
        cnt[i] = 0;
}

__global__ void count_agents(const int* __restrict__ coords,
                             int* __restrict__ cnt, int n) {
    const int stride = gridDim.x * blockDim.x;
    for (int i = blockIdx.x * blockDim.x + threadIdx.x; i < n; i += stride)
        atomicAdd(&cnt[coords[i]], 1);
}

// Per-block exclusive scan of cnt -> offs (partial), block totals -> bsum.
__global__ void scan_blocks(const int* __restrict__ cnt, int* __restrict__ offs,
                            int* __restrict__ bsum, int n) {
    __shared__ int s[256];
    const int t = threadIdx.x;
    const int idx = blockIdx.x * 256 + t;
    const int v = (idx < n) ? cnt[idx] : 0;
    s[t] = v;
    __syncthreads();
    for (int off = 1; off < 256; off <<= 1) {
        int x = (t >= off) ? s[t - off] : 0;
        __syncthreads();
        s[t] += x;
        __syncthreads();
    }
    if (idx < n) offs[idx] = s[t] - v;  // exclusive within block
    if (t == 255) bsum[blockIdx.x] = s[255];
}

// Single-block exclusive scan of bsum[nb] in place.
__global__ void scan_carry(int* __restrict__ bsum, int nb) {
    __shared__ int s[256];
    __shared__ int carry;
    const int t = threadIdx.x;
    if (t == 0) carry = 0;
    __syncthreads();
    for (int base = 0; base < nb; base += 256) {
        const int v = (base + t < nb) ? bsum[base + t] : 0;
        s[t] = v;
        __syncthreads();
        for (int off = 1; off < 256; off <<= 1) {
            int x = (t >= off) ? s[t - off] : 0;
            __syncthreads();
            s[t] += x;
            __syncthreads();
        }
        const int tot = s[255];
        const int ex = carry + s[t] - v;
        if (base + t < nb) bsum[base + t] = ex;
        __syncthreads();  // all reads of carry/s done before update
        if (t == 0) carry += tot;
        __syncthreads();
    }
}

__global__ void finalize_offs(int* __restrict__ offs, int* __restrict__ wptr,
                              const int* __restrict__ bsum, int n) {
    const int stride = gridDim.x * blockDim.x;
    for (int i = blockIdx.x * blockDim.x + threadIdx.x; i < n; i += stride) {
        const int o = offs[i] + bsum[i >> 8];
        offs[i] = o;
        wptr[i] = o;
    }
}

__global__ void fill_order(const int* __restrict__ coords,
                           int* __restrict__ wptr, int* __restrict__ order,
                           int n) {
    const int stride = gridDim.x * blockDim.x;
    for (int i = blockIdx.x * blockDim.x + threadIdx.x; i < n; i += stride) {
        const int pos = atomicAdd(&wptr[coords[i]], 1);
        order[pos] = i;
    }
}

// ---------------- gather ----------------
// Block = 512 threads = 32 cells x 16 lanes; each lane owns 4 channels.
// Grid: x = ceil(10000/32) chunks within a batch plane, y = batch.
__global__ __launch_bounds__(512) void gather_csr(
    const float* __restrict__ enc, const int* __restrict__ offs,
    const int* __restrict__ cnt, const int* __restrict__ order,
    float* __restrict__ out) {
    __shared__ float tile[CPB][C_DIM + 1];
    const int tid = threadIdx.x;
    const int cl = tid >> 4;
    const int c4 = (tid & 15) << 2;
    const int b = blockIdx.y;
    const int rem0 = blockIdx.x * CPB;
    const int rem = rem0 + cl;

    int start = 0, L = 0;
    if (rem < CELLS_PER_B) {
        const int cell = b * CELLS_PER_B + rem;
        start = offs[cell];
        L = cnt[cell];
    }
    float4 m = make_float4(-INFINITY, -INFINITY, -INFINITY, -INFINITY);
#pragma unroll 4
    for (int i = 0; i < L; ++i) {
        const int a = order[start + i];  // broadcast across the 16 lanes
        const float4 v =
            *reinterpret_cast<const float4*>(enc + (size_t)a * C_DIM + c4);
        m.x = fmaxf(m.x, v.x);
        m.y = fmaxf(m.y, v.y);
        m.z = fmaxf(m.z, v.z);
        m.w = fmaxf(m.w, v.w);
    }
    if (L == 0) m = make_float4(0.f, 0.f, 0.f, 0.f);
    tile[cl][c4 + 0] = m.x;
    tile[cl][c4 + 1] = m.y;
    tile[cl][c4 + 2] = m.z;
    tile[cl][c4 + 3] = m.w;
    __syncthreads();

    float* base = out + ((size_t)b * C_DIM) * CELLS_PER_B + rem0;
    const int limit = min(CPB, CELLS_PER_B - rem0);
    for (int i = tid; i < CPB * C_DIM; i += 512) {
        const int c = i >> 5;
        const int j = i & 31;
        if (j < limit) base[(size_t)c * CELLS_PER_B + j] = tile[j][c];
    }
}

// ---------------- fallback: round-3 linked-list path ----------------
__global__ void init_head(int* __restrict__ head, int n) {
    const int stride = gridDim.x * blockDim.x;
    for (int i = blockIdx.x * blockDim.x + threadIdx.x; i < n; i += stride)
        head[i] = -1;
}
__global__ void build_lists(const int* __restrict__ coords,
                            int* __restrict__ head, int* __restrict__ next,
                            int n) {
    const int stride = gridDim.x * blockDim.x;
    for (int i = blockIdx.x * blockDim.x + threadIdx.x; i < n; i += stride) {
        const int c = coords[i];
        next[i] = atomicExch(&head[c], i);
    }
}
__global__ __launch_bounds__(512) void gather_ll(
    const float* __restrict__ enc, const int* __restrict__ head,
    const int* __restrict__ next, float* __restrict__ out) {
    __shared__ float tile[CPB][C_DIM + 1];
    const int tid = threadIdx.x;
    const int cl = tid >> 4;
    const int c4 = (tid & 15) << 2;
    const int b = blockIdx.y;
    const int rem0 = blockIdx.x * CPB;
    const int rem = rem0 + cl;

    float4 m = make_float4(-INFINITY, -INFINITY, -INFINITY, -INFINITY);
    int agent = (rem < CELLS_PER_B) ? head[b * CELLS_PER_B + rem] : -1;
    const bool occupied = (agent >= 0);
    while (agent >= 0) {
        const int nxt = next[agent];
        const float4 v =
            *reinterpret_cast<const float4*>(enc + (size_t)agent * C_DIM + c4);
        m.x = fmaxf(m.x, v.x);
        m.y = fmaxf(m.y, v.y);
        m.z = fmaxf(m.z, v.z);
        m.w = fmaxf(m.w, v.w);
        agent = nxt;
    }
    if (!occupied) m = make_float4(0.f, 0.f, 0.f, 0.f);
    tile[cl][c4 + 0] = m.x;
    tile[cl][c4 + 1] = m.y;
    tile[cl][c4 + 2] = m.z;
    tile[cl][c4 + 3] = m.w;
    __syncthreads();
    float* base = out + ((size_t)b * C_DIM) * CELLS_PER_B + rem0;
    const int limit = min(CPB, CELLS_PER_B - rem0);
    for (int i = tid; i < CPB * C_DIM; i += 512) {
        const int c = i >> 5;
        const int j = i & 31;
        if (j < limit) base[(size_t)c * CELLS_PER_B + j] = tile[j][c];
    }
}

extern "C" void kernel_launch(void* const* d_in, const int* in_sizes, int n_in,
                              void* d_out, int out_size, void* d_ws, size_t ws_size,
                              hipStream_t stream) {
    const float* enc = (const float*)d_in[1];
    const int* coords = (const int*)d_in[2];
    const int n = in_sizes[2];
    const int ncells = out_size / C_DIM;  // B * 10000
    const int B = ncells / CELLS_PER_B;
    const int nb = (ncells + 255) / 256;

    const size_t need_csr =
        ((size_t)3 * ncells + (size_t)n + (size_t)nb) * sizeof(int);
    dim3 ggrid((CELLS_PER_B + CPB - 1) / CPB, B);

    if (ws_size >= need_csr) {
        int* cnt = (int*)d_ws;
        int* offs = cnt + ncells;
        int* wptr = offs + ncells;
        int* order = wptr + ncells;
        int* bsum = order + n;

        init_counts<<<512, 256, 0, stream>>>(cnt, ncells);
        count_agents<<<2048, 256, 0, stream>>>(coords, cnt, n);
        scan_blocks<<<nb, 256, 0, stream>>>(cnt, offs, bsum, ncells);
        scan_carry<<<1, 256, 0, stream>>>(bsum, nb);
        finalize_offs<<<512, 256, 0, stream>>>(offs, wptr, bsum, ncells);
        fill_order<<<2048, 256, 0, stream>>>(coords, wptr, order, n);
        gather_csr<<<ggrid, 512, 0, stream>>>(enc, offs, cnt, order,
                                              (float*)d_out);
    } else {
        int* head = (int*)d_ws;
        int* next = head + ncells;
        init_head<<<512, 256, 0, stream>>>(head, ncells);
        build_lists<<<2048, 256, 0, stream>>>(coords, head, next, n);
        gather_ll<<<ggrid, 512, 0, stream>>>(enc, head, next, (float*)d_out);
    }
}

// Round 5
// 187.918 us; speedup vs baseline: 1.1552x; 1.1552x over previous
//
#include <hip/hip_runtime.h>
#include <math.h>

// SpatialEncodeAgent: segment_max of agent_encodings (N,64) into a B*100*100
// grid, output [B, C, S, S] f32, 0 for empty cells.
//
// Round-5: back to the linked-list gather (round-4's CSR build cost +85 us
// and proved the pointer-chase was not the gather's limiter). Changes vs
// round 3:
//  - gather: ONE chain per wave (64 lanes = 64 channels, 4B/lane = one
//    coalesced 256B row read). Removes intra-wave chain-length divergence
//    (was max-of-4 Poisson(3.1) ~ 1.7x wasted iterations); head/next loads
//    are wave-uniform broadcasts. Each wave walks 4 cells sequentially.
//  - build_lists: int4 coord reads, next[] written as one int4 store.
// fmax is exactly commutative -> chain-order nondeterminism is bitwise-safe.

#define S_DIM 100
#define CELLS_PER_B (S_DIM * S_DIM)  // 10000
#define C_DIM 64
#define CPB 32  // cells per gather block (8 waves x 4 cells each)

__global__ void init_head(int* __restrict__ head, int n) {
    const int stride = gridDim.x * blockDim.x;
    for (int i = blockIdx.x * blockDim.x + threadIdx.x; i < n; i += stride)
        head[i] = -1;
}

__global__ void build_lists(const int* __restrict__ coords,
                            int* __restrict__ head, int* __restrict__ next,
                            int n) {
    const int n4 = n >> 2;
    const int stride = gridDim.x * blockDim.x;
    const int4* c4p = reinterpret_cast<const int4*>(coords);
    for (int i = blockIdx.x * blockDim.x + threadIdx.x; i < n4; i += stride) {
        const int4 c = c4p[i];
        const int base = i << 2;
        int4 nx;
        nx.x = atomicExch(&head[c.x], base + 0);
        nx.y = atomicExch(&head[c.y], base + 1);
        nx.z = atomicExch(&head[c.z], base + 2);
        nx.w = atomicExch(&head[c.w], base + 3);
        reinterpret_cast<int4*>(next)[i] = nx;
    }
    // tail (n not divisible by 4)
    const int tail0 = n4 << 2;
    const int gtid = blockIdx.x * blockDim.x + threadIdx.x;
    if (gtid < n - tail0) {
        const int i = tail0 + gtid;
        next[i] = atomicExch(&head[coords[i]], i);
    }
}

// Block = 512 threads = 8 waves; each wave owns 4 cells (walked sequentially,
// 64 lanes = 64 channels -> one 256B coalesced row read per chain step).
// Grid: x = ceil(10000/CPB) chunks in a batch plane, y = batch.
__global__ __launch_bounds__(512) void gather_ll(
    const float* __restrict__ enc, const int* __restrict__ head,
    const int* __restrict__ next, float* __restrict__ out) {
    __shared__ float tile[CPB][C_DIM + 1];  // +1 pad: conflict-free transpose
    const int tid = threadIdx.x;
    const int lane = tid & 63;
    const int wave = tid >> 6;  // 0..7
    const int b = blockIdx.y;
    const int rem0 = blockIdx.x * CPB;

#pragma unroll
    for (int k = 0; k < CPB / 8; ++k) {
        const int cl = wave + (k << 3);  // local cell handled by this wave
        const int rem = rem0 + cl;
        float m = -INFINITY;
        int agent = (rem < CELLS_PER_B) ? head[b * CELLS_PER_B + rem] : -1;
        const bool occupied = (agent >= 0);
        while (agent >= 0) {
            const int nxt = next[agent];  // wave-uniform; independent of enc read
            m = fmaxf(m, enc[(size_t)agent * C_DIM + lane]);
            agent = nxt;
        }
        tile[cl][lane] = occupied ? m : 0.f;
    }
    __syncthreads();

    // Transposed write: per channel c, 32 lanes store 32 consecutive cells
    // (full 128B line; rem0 is 32-float aligned).
    float* base = out + ((size_t)b * C_DIM) * CELLS_PER_B + rem0;
    const int limit = min(CPB, CELLS_PER_B - rem0);
    for (int i = tid; i < CPB * C_DIM; i += 512) {
        const int c = i >> 5;
        const int j = i & 31;
        if (j < limit) base[(size_t)c * CELLS_PER_B + j] = tile[j][c];
    }
}

// ---------- fallback (atomic scatter) if ws too small ----------
__device__ __forceinline__ unsigned encode_f32(float f) {
    unsigned u = __float_as_uint(f);
    return (u & 0x80000000u) ? ~u : (u | 0x80000000u);
}
__device__ __forceinline__ float decode_key(unsigned k) {
    if (k == 0u) return 0.0f;
    return (k & 0x80000000u) ? __uint_as_float(k & 0x7FFFFFFFu)
                             : __uint_as_float(~k);
}
__global__ void spatial_scatter_max(const float* __restrict__ enc,
                                    const int* __restrict__ coords,
                                    unsigned* __restrict__ grid, int n_agents) {
    const long long total = (long long)n_agents * 16;
    const long long stride = (long long)gridDim.x * blockDim.x;
    for (long long i = (long long)blockIdx.x * blockDim.x + threadIdx.x;
         i < total; i += stride) {
        const int agent = (int)(i >> 4);
        const int c4 = ((int)i & 15) << 2;
        const int coord = coords[agent];
        const int b = coord / CELLS_PER_B;
        const int rem = coord - b * CELLS_PER_B;
        const float4 v =
            *reinterpret_cast<const float4*>(enc + (size_t)agent * C_DIM + c4);
        unsigned* p = grid + ((size_t)b * C_DIM + c4) * CELLS_PER_B + rem;
        atomicMax(p, encode_f32(v.x));
        atomicMax(p + 1 * CELLS_PER_B, encode_f32(v.y));
        atomicMax(p + 2 * CELLS_PER_B, encode_f32(v.z));
        atomicMax(p + 3 * CELLS_PER_B, encode_f32(v.w));
    }
}
__global__ void spatial_decode(unsigned* __restrict__ grid, int n4) {
    const int stride = gridDim.x * blockDim.x;
    uint4* g4 = reinterpret_cast<uint4*>(grid);
    for (int i = blockIdx.x * blockDim.x + threadIdx.x; i < n4; i += stride) {
        uint4 k = g4[i];
        float4 f;
        f.x = decode_key(k.x);
        f.y = decode_key(k.y);
        f.z = decode_key(k.z);
        f.w = decode_key(k.w);
        reinterpret_cast<float4*>(g4)[i] = f;
    }
}

extern "C" void kernel_launch(void* const* d_in, const int* in_sizes, int n_in,
                              void* d_out, int out_size, void* d_ws, size_t ws_size,
                              hipStream_t stream) {
    const float* enc = (const float*)d_in[1];
    const int* coords = (const int*)d_in[2];
    const int n = in_sizes[2];
    const int ncells = out_size / C_DIM;  // B * 10000
    const int B = ncells / CELLS_PER_B;

    const size_t need = ((size_t)ncells + (size_t)n) * sizeof(int);
    if (ws_size >= need) {
        int* head = (int*)d_ws;
        int* next = head + ncells;
        init_head<<<512, 256, 0, stream>>>(head, ncells);
        build_lists<<<1024, 256, 0, stream>>>(coords, head, next, n);
        dim3 grid((CELLS_PER_B + CPB - 1) / CPB, B);  // (313, B)
        gather_ll<<<grid, 512, 0, stream>>>(enc, head, next, (float*)d_out);
    } else {
        unsigned* out = (unsigned*)d_out;
        hipMemsetAsync(d_out, 0, (size_t)out_size * sizeof(float), stream);
        spatial_scatter_max<<<2048, 256, 0, stream>>>(enc, coords, out, n);
        spatial_decode<<<2048, 256, 0, stream>>>(out, out_size / 4);
    }
}

// Round 6
// 169.550 us; speedup vs baseline: 1.2804x; 1.1083x over previous
//
#include <hip/hip_runtime.h>
#include <math.h>

// SpatialEncodeAgent: segment_max of agent_encodings (N,64) into a B*100*100
// grid, output [B, C, S, S] f32, 0 for empty cells.
//
// Round-6: bucket-CSR. Round-5 counters showed the gather is LATENCY-bound
// (1.0-1.5 TB/s, 12% HBM, 85% occupancy): the linked-list next[agent] load is
// a dependent chain that caps bytes-in-flight per wave. Fix: single-pass
// bucket build (atomicAdd slot counter, 16 slots/cell, rare overflow chain)
// gives the gather all agent addresses upfront -> counted, independent
// iterations the compiler can pipeline -> ~4-8x more enc bytes in flight.
// Build is ONE pass (no scan kernels - round-4's CSR build cost +85 us).
// fmax is exactly commutative -> bucket-order nondeterminism is bitwise-safe.

#define S_DIM 100
#define CELLS_PER_B (S_DIM * S_DIM)  // 10000
#define C_DIM 64
#define CPB 32      // cells per gather block
#define K_SLOTS 16  // bucket capacity; P(count>16) ~ 1e-4 over the dataset

__global__ void init_meta(int* __restrict__ cnt, int* __restrict__ ohead,
                          int n) {
    const int stride = gridDim.x * blockDim.x;
    for (int i = blockIdx.x * blockDim.x + threadIdx.x; i < n; i += stride) {
        cnt[i] = 0;
        ohead[i] = -1;
    }
}

__device__ __forceinline__ void bucket_insert(int cc, int a,
                                              int* __restrict__ cnt,
                                              int* __restrict__ ohead,
                                              int* __restrict__ slot,
                                              int* __restrict__ next) {
    const int pos = atomicAdd(&cnt[cc], 1);
    if (pos < K_SLOTS)
        slot[(size_t)cc * K_SLOTS + pos] = a;
    else
        next[a] = atomicExch(&ohead[cc], a);  // rare overflow chain
}

__global__ void build_buckets(const int* __restrict__ coords,
                              int* __restrict__ cnt, int* __restrict__ ohead,
                              int* __restrict__ slot, int* __restrict__ next,
                              int n) {
    const int n4 = n >> 2;
    const int stride = gridDim.x * blockDim.x;
    const int4* c4p = reinterpret_cast<const int4*>(coords);
    for (int i = blockIdx.x * blockDim.x + threadIdx.x; i < n4; i += stride) {
        const int4 c = c4p[i];
        const int base = i << 2;
        bucket_insert(c.x, base + 0, cnt, ohead, slot, next);
        bucket_insert(c.y, base + 1, cnt, ohead, slot, next);
        bucket_insert(c.z, base + 2, cnt, ohead, slot, next);
        bucket_insert(c.w, base + 3, cnt, ohead, slot, next);
    }
    const int tail0 = n4 << 2;
    const int g = blockIdx.x * blockDim.x + threadIdx.x;
    if (g < n - tail0)
        bucket_insert(coords[tail0 + g], tail0 + g, cnt, ohead, slot, next);
}

// Block = 512 threads = 32 cells x 16 lanes; lane owns 4 channels (float4).
// Slot indices for a wave's 4 cells are loaded as ONE coalesced 256B read
// (addr = base*16 + tid), then broadcast per iteration via __shfl within the
// cell's 16-lane group -> loop iterations carry no load dependence.
__global__ __launch_bounds__(512) void gather_buckets(
    const float* __restrict__ enc, const int* __restrict__ cnt,
    const int* __restrict__ ohead, const int* __restrict__ slot,
    const int* __restrict__ next, float* __restrict__ out) {
    __shared__ float tile[CPB][C_DIM + 1];  // +1 pad: conflict-free transpose
    const int tid = threadIdx.x;
    const int cl = tid >> 4;         // local cell 0..31
    const int c4 = (tid & 15) << 2;  // channel base 0,4,...,60
    const int lane = tid & 63;
    const int grp = lane & 48;  // first lane of this cell's 16-lane group
    const int b = blockIdx.y;
    const int rem0 = blockIdx.x * CPB;
    const int rem = rem0 + cl;
    const int cell = b * CELLS_PER_B + rem;

    int L0 = 0, aval = 0;
    if (rem < CELLS_PER_B) {
        L0 = cnt[cell];
        // fully-coalesced: index = (b*CELLS_PER_B + rem0)*16 + tid
        aval = slot[((size_t)(b * CELLS_PER_B + rem0) << 4) + tid];
    }

    float4 m = make_float4(-INFINITY, -INFINITY, -INFINITY, -INFINITY);
    const int L = min(L0, K_SLOTS);
#pragma unroll 4
    for (int i = 0; i < L; ++i) {
        const int a = __shfl(aval, grp + i, 64);  // src lane in own active grp
        const float4 v =
            *reinterpret_cast<const float4*>(enc + (size_t)a * C_DIM + c4);
        m.x = fmaxf(m.x, v.x);
        m.y = fmaxf(m.y, v.y);
        m.z = fmaxf(m.z, v.z);
        m.w = fmaxf(m.w, v.w);
    }
    if (L0 > K_SLOTS) {  // rare overflow: walk the chain
        int a = ohead[cell];
        while (a >= 0) {
            const float4 v =
                *reinterpret_cast<const float4*>(enc + (size_t)a * C_DIM + c4);
            m.x = fmaxf(m.x, v.x);
            m.y = fmaxf(m.y, v.y);
            m.z = fmaxf(m.z, v.z);
            m.w = fmaxf(m.w, v.w);
            a = next[a];
        }
    }
    if (L0 == 0) m = make_float4(0.f, 0.f, 0.f, 0.f);
    tile[cl][c4 + 0] = m.x;
    tile[cl][c4 + 1] = m.y;
    tile[cl][c4 + 2] = m.z;
    tile[cl][c4 + 3] = m.w;
    __syncthreads();

    // Transposed write: per channel, 32 lanes store 32 consecutive cells
    // (full 128B line; rem0 is 32-float aligned).
    float* base = out + ((size_t)b * C_DIM) * CELLS_PER_B + rem0;
    const int limit = min(CPB, CELLS_PER_B - rem0);
    for (int i = tid; i < CPB * C_DIM; i += 512) {
        const int c = i >> 5;
        const int j = i & 31;
        if (j < limit) base[(size_t)c * CELLS_PER_B + j] = tile[j][c];
    }
}

// ---------- fallback (atomic scatter) if ws too small ----------
__device__ __forceinline__ unsigned encode_f32(float f) {
    unsigned u = __float_as_uint(f);
    return (u & 0x80000000u) ? ~u : (u | 0x80000000u);
}
__device__ __forceinline__ float decode_key(unsigned k) {
    if (k == 0u) return 0.0f;
    return (k & 0x80000000u) ? __uint_as_float(k & 0x7FFFFFFFu)
                             : __uint_as_float(~k);
}
__global__ void spatial_scatter_max(const float* __restrict__ enc,
                                    const int* __restrict__ coords,
                                    unsigned* __restrict__ grid, int n_agents) {
    const long long total = (long long)n_agents * 16;
    const long long stride = (long long)gridDim.x * blockDim.x;
    for (long long i = (long long)blockIdx.x * blockDim.x + threadIdx.x;
         i < total; i += stride) {
        const int agent = (int)(i >> 4);
        const int c4 = ((int)i & 15) << 2;
        const int coord = coords[agent];
        const int b = coord / CELLS_PER_B;
        const int rem = coord - b * CELLS_PER_B;
        const float4 v =
            *reinterpret_cast<const float4*>(enc + (size_t)agent * C_DIM + c4);
        unsigned* p = grid + ((size_t)b * C_DIM + c4) * CELLS_PER_B + rem;
        atomicMax(p, encode_f32(v.x));
        atomicMax(p + 1 * CELLS_PER_B, encode_f32(v.y));
        atomicMax(p + 2 * CELLS_PER_B, encode_f32(v.z));
        atomicMax(p + 3 * CELLS_PER_B, encode_f32(v.w));
    }
}
__global__ void spatial_decode(unsigned* __restrict__ grid, int n4) {
    const int stride = gridDim.x * blockDim.x;
    uint4* g4 = reinterpret_cast<uint4*>(grid);
    for (int i = blockIdx.x * blockDim.x + threadIdx.x; i < n4; i += stride) {
        uint4 k = g4[i];
        float4 f;
        f.x = decode_key(k.x);
        f.y = decode_key(k.y);
        f.z = decode_key(k.z);
        f.w = decode_key(k.w);
        reinterpret_cast<float4*>(g4)[i] = f;
    }
}

extern "C" void kernel_launch(void* const* d_in, const int* in_sizes, int n_in,
                              void* d_out, int out_size, void* d_ws, size_t ws_size,
                              hipStream_t stream) {
    const float* enc = (const float*)d_in[1];
    const int* coords = (const int*)d_in[2];
    const int n = in_sizes[2];
    const int ncells = out_size / C_DIM;  // B * 10000
    const int B = ncells / CELLS_PER_B;

    // ws layout: cnt[ncells] | ohead[ncells] | slot[ncells*16] | next[n]
    const size_t need =
        ((size_t)ncells * (2 + K_SLOTS) + (size_t)n) * sizeof(int);
    if (ws_size >= need) {
        int* cnt = (int*)d_ws;
        int* ohead = cnt + ncells;
        int* slot = ohead + ncells;
        int* next = slot + (size_t)ncells * K_SLOTS;

        init_meta<<<512, 256, 0, stream>>>(cnt, ohead, ncells);
        build_buckets<<<1024, 256, 0, stream>>>(coords, cnt, ohead, slot, next,
                                                n);
        dim3 grid((CELLS_PER_B + CPB - 1) / CPB, B);  // (313, B)
        gather_buckets<<<grid, 512, 0, stream>>>(enc, cnt, ohead, slot, next,
                                                 (float*)d_out);
    } else {
        unsigned* out = (unsigned*)d_out;
        hipMemsetAsync(d_out, 0, (size_t)out_size * sizeof(float), stream);
        spatial_scatter_max<<<2048, 256, 0, stream>>>(enc, coords, out, n);
        spatial_decode<<<2048, 256, 0, stream>>>(out, out_size / 4);
    }
}

// Round 7
// 117.042 us; speedup vs baseline: 1.8548x; 1.4486x over previous
//
#include <hip/hip_runtime.h>
#include <math.h>

// SpatialEncodeAgent: segment_max of agent_encodings (N,64) into a B*100*100
// grid, output [B, C, S, S] f32, 0 for empty cells.
//
// Round-7: LL build (round-2's, coalesced next[] writes - cheap) + MLP-4x
// gather. Evidence: effective gather BW scaled with chains/wave (round 5:
// 1 chain/wave -> 1.0 TB/s; round 2/3: 4 chains/wave -> ~3.8 TB/s) => the
// gather is MLP-limited, not BW- or dependence-limited. Each 16-lane group
// now walks 4 chains at once (16 chains/wave); the loop body issues 4 next +
// 4 enc-row loads UNCONDITIONALLY (dead chains load row 0, L1-resident) so
// ~4KB/wave is in flight before any consumer. Output stores are nontemporal
// to preserve L3 retention of enc across replays (round-5 FETCH=174MB <
// 256MB enc proved L3 retention matters).
// fmax is exactly commutative -> chain-order nondeterminism is bitwise-safe.

#define S_DIM 100
#define CELLS_PER_B (S_DIM * S_DIM)  // 10000
#define C_DIM 64
#define CPB 64  // cells per gather block (256 thr = 16 groups x 4 chains)

typedef float fvec4 __attribute__((ext_vector_type(4)));

__device__ __forceinline__ fvec4 max4(fvec4 a, fvec4 b) {
    fvec4 r;
    r.x = fmaxf(a.x, b.x);
    r.y = fmaxf(a.y, b.y);
    r.z = fmaxf(a.z, b.z);
    r.w = fmaxf(a.w, b.w);
    return r;
}

__global__ void init_head(int* __restrict__ head, int n) {
    const int stride = gridDim.x * blockDim.x;
    for (int i = blockIdx.x * blockDim.x + threadIdx.x; i < n; i += stride)
        head[i] = -1;
}

__global__ void build_lists(const int* __restrict__ coords,
                            int* __restrict__ head, int* __restrict__ next,
                            int n) {
    const int n4 = n >> 2;
    const int stride = gridDim.x * blockDim.x;
    const int4* c4p = reinterpret_cast<const int4*>(coords);
    for (int i = blockIdx.x * blockDim.x + threadIdx.x; i < n4; i += stride) {
        const int4 c = c4p[i];
        const int base = i << 2;
        int4 nx;
        nx.x = atomicExch(&head[c.x], base + 0);
        nx.y = atomicExch(&head[c.y], base + 1);
        nx.z = atomicExch(&head[c.z], base + 2);
        nx.w = atomicExch(&head[c.w], base + 3);
        reinterpret_cast<int4*>(next)[i] = nx;  // coalesced
    }
    const int tail0 = n4 << 2;
    const int g = blockIdx.x * blockDim.x + threadIdx.x;
    if (g < n - tail0) {
        const int i = tail0 + g;
        next[i] = atomicExch(&head[coords[i]], i);
    }
}

// Block = 256 threads = 16 groups of 16 lanes; each group walks 4 chains
// (4 consecutive cells). Lane owns 4 channels (float4 of the 256B row).
// Grid: x = ceil(10000/CPB) chunks within a batch plane, y = batch.
__global__ __launch_bounds__(256) void gather_ll4(
    const float* __restrict__ enc, const int* __restrict__ head,
    const int* __restrict__ next, float* __restrict__ out) {
    __shared__ float tile[CPB][C_DIM + 1];  // +1 pad: conflict-free transpose
    const int tid = threadIdx.x;
    const int grp = tid >> 4;  // 0..15
    const int l16 = tid & 15;
    const int b = blockIdx.y;
    const int rem0 = blockIdx.x * CPB;
    const int cbase = rem0 + (grp << 2);  // first of this group's 4 cells
    const long long cell0 = (long long)b * CELLS_PER_B + cbase;

    int a0 = (cbase + 0 < CELLS_PER_B) ? head[cell0 + 0] : -1;
    int a1 = (cbase + 1 < CELLS_PER_B) ? head[cell0 + 1] : -1;
    int a2 = (cbase + 2 < CELLS_PER_B) ? head[cell0 + 2] : -1;
    int a3 = (cbase + 3 < CELLS_PER_B) ? head[cell0 + 3] : -1;
    const bool o0 = a0 >= 0, o1 = a1 >= 0, o2 = a2 >= 0, o3 = a3 >= 0;

    const fvec4* enc4 = reinterpret_cast<const fvec4*>(enc);
    fvec4 m0 = {-INFINITY, -INFINITY, -INFINITY, -INFINITY};
    fvec4 m1 = m0, m2 = m0, m3 = m0;

    while (a0 >= 0 || a1 >= 0 || a2 >= 0 || a3 >= 0) {
        // clamp dead chains to row 0 so ALL loads issue unconditionally
        const int i0 = a0 >= 0 ? a0 : 0;
        const int i1 = a1 >= 0 ? a1 : 0;
        const int i2 = a2 >= 0 ? a2 : 0;
        const int i3 = a3 >= 0 ? a3 : 0;
        const int n0 = next[i0];
        const int n1 = next[i1];
        const int n2 = next[i2];
        const int n3 = next[i3];
        const fvec4 v0 = enc4[(size_t)i0 * 16 + l16];
        const fvec4 v1 = enc4[(size_t)i1 * 16 + l16];
        const fvec4 v2 = enc4[(size_t)i2 * 16 + l16];
        const fvec4 v3 = enc4[(size_t)i3 * 16 + l16];
        if (a0 >= 0) { m0 = max4(m0, v0); a0 = n0; }
        if (a1 >= 0) { m1 = max4(m1, v1); a1 = n1; }
        if (a2 >= 0) { m2 = max4(m2, v2); a2 = n2; }
        if (a3 >= 0) { m3 = max4(m3, v3); a3 = n3; }
    }
    if (!o0) m0 = (fvec4){0.f, 0.f, 0.f, 0.f};
    if (!o1) m1 = (fvec4){0.f, 0.f, 0.f, 0.f};
    if (!o2) m2 = (fvec4){0.f, 0.f, 0.f, 0.f};
    if (!o3) m3 = (fvec4){0.f, 0.f, 0.f, 0.f};

    const int r = grp << 2;
    const int cb = l16 << 2;
    tile[r + 0][cb + 0] = m0.x; tile[r + 0][cb + 1] = m0.y;
    tile[r + 0][cb + 2] = m0.z; tile[r + 0][cb + 3] = m0.w;
    tile[r + 1][cb + 0] = m1.x; tile[r + 1][cb + 1] = m1.y;
    tile[r + 1][cb + 2] = m1.z; tile[r + 1][cb + 3] = m1.w;
    tile[r + 2][cb + 0] = m2.x; tile[r + 2][cb + 1] = m2.y;
    tile[r + 2][cb + 2] = m2.z; tile[r + 2][cb + 3] = m2.w;
    tile[r + 3][cb + 0] = m3.x; tile[r + 3][cb + 1] = m3.y;
    tile[r + 3][cb + 2] = m3.z; tile[r + 3][cb + 3] = m3.w;
    __syncthreads();

    // Transposed write: per channel c, 64 lanes store 64 consecutive cells
    // (256B, line-aligned since rem0 is a multiple of 64). Nontemporal to
    // keep out-lines from evicting enc in L3.
    float* base = out + ((size_t)b * C_DIM) * CELLS_PER_B + rem0;
    const int limit = min(CPB, CELLS_PER_B - rem0);
    for (int i = tid; i < CPB * C_DIM; i += 256) {
        const int c = i >> 6;
        const int j = i & 63;
        if (j < limit)
            __builtin_nontemporal_store(tile[j][c],
                                        &base[(size_t)c * CELLS_PER_B + j]);
    }
}

// ---------- fallback (atomic scatter) if ws too small ----------
__device__ __forceinline__ unsigned encode_f32(float f) {
    unsigned u = __float_as_uint(f);
    return (u & 0x80000000u) ? ~u : (u | 0x80000000u);
}
__device__ __forceinline__ float decode_key(unsigned k) {
    if (k == 0u) return 0.0f;
    return (k & 0x80000000u) ? __uint_as_float(k & 0x7FFFFFFFu)
                             : __uint_as_float(~k);
}
__global__ void spatial_scatter_max(const float* __restrict__ enc,
                                    const int* __restrict__ coords,
                                    unsigned* __restrict__ grid, int n_agents) {
    const long long total = (long long)n_agents * 16;
    const long long stride = (long long)gridDim.x * blockDim.x;
    for (long long i = (long long)blockIdx.x * blockDim.x + threadIdx.x;
         i < total; i += stride) {
        const int agent = (int)(i >> 4);
        const int c4 = ((int)i & 15) << 2;
        const int coord = coords[agent];
        const int b = coord / CELLS_PER_B;
        const int rem = coord - b * CELLS_PER_B;
        const float4 v =
            *reinterpret_cast<const float4*>(enc + (size_t)agent * C_DIM + c4);
        unsigned* p = grid + ((size_t)b * C_DIM + c4) * CELLS_PER_B + rem;
        atomicMax(p, encode_f32(v.x));
        atomicMax(p + 1 * CELLS_PER_B, encode_f32(v.y));
        atomicMax(p + 2 * CELLS_PER_B, encode_f32(v.z));
        atomicMax(p + 3 * CELLS_PER_B, encode_f32(v.w));
    }
}
__global__ void spatial_decode(unsigned* __restrict__ grid, int n4) {
    const int stride = gridDim.x * blockDim.x;
    uint4* g4 = reinterpret_cast<uint4*>(grid);
    for (int i = blockIdx.x * blockDim.x + threadIdx.x; i < n4; i += stride) {
        uint4 k = g4[i];
        float4 f;
        f.x = decode_key(k.x);
        f.y = decode_key(k.y);
        f.z = decode_key(k.z);
        f.w = decode_key(k.w);
        reinterpret_cast<float4*>(g4)[i] = f;
    }
}

extern "C" void kernel_launch(void* const* d_in, const int* in_sizes, int n_in,
                              void* d_out, int out_size, void* d_ws, size_t ws_size,
                              hipStream_t stream) {
    const float* enc = (const float*)d_in[1];
    const int* coords = (const int*)d_in[2];
    const int n = in_sizes[2];
    const int ncells = out_size / C_DIM;  // B * 10000
    const int B = ncells / CELLS_PER_B;

    const size_t need = ((size_t)ncells + (size_t)n) * sizeof(int);
    if (ws_size >= need) {
        int* head = (int*)d_ws;
        int* next = head + ncells;
        init_head<<<512, 256, 0, stream>>>(head, ncells);
        build_lists<<<1024, 256, 0, stream>>>(coords, head, next, n);
        dim3 grid((CELLS_PER_B + CPB - 1) / CPB, B);  // (157, B)
        gather_ll4<<<grid, 256, 0, stream>>>(enc, head, next, (float*)d_out);
    } else {
        unsigned* out = (unsigned*)d_out;
        hipMemsetAsync(d_out, 0, (size_t)out_size * sizeof(float), stream);
        spatial_scatter_max<<<2048, 256, 0, stream>>>(enc, coords, out, n);
        spatial_decode<<<2048, 256, 0, stream>>>(out, out_size / 4);
    }
}